// Round 17
// baseline (10439.980 us; speedup 1.0000x reference)
//
#include <hip/hip_runtime.h>
#include <stdint.h>

typedef unsigned short u16;
typedef unsigned int   u32;
typedef unsigned long long u64;
typedef __attribute__((ext_vector_type(8))) short short8;
typedef __attribute__((ext_vector_type(4))) short s16x4;
typedef __attribute__((ext_vector_type(4))) float f32x4;

#define MFMA(a,b,c) __builtin_amdgcn_mfma_f32_16x16x32_bf16((a),(b),(c),0,0,0)
#define NBLK 256
#define NTHR 256
// LDS: ep 128K | sB 4K | sA 1K | sRed 64B | sAcc 24K  = 160832 <= 163840
#define SMEM_BYTES 160832

static const long kOutB = 256*1024;   // per-batch stride in out/input [64,256,1024]

__device__ __forceinline__ float b2f(u16 v){ union{u32 u; float f;} c; c.u = ((u32)v)<<16; return c.f; }
__device__ __forceinline__ u16 f2b(float f){ union{float f; u32 u;} c; c.f = f; u32 r = c.u + 0x7FFFu + ((c.u>>16)&1u); return (u16)(r>>16); }
__device__ __forceinline__ float fexp2(float x){ return __builtin_amdgcn_exp2f(x); }
__device__ __forceinline__ float frcp(float x){ return __builtin_amdgcn_rcpf(x); }
__device__ __forceinline__ float tanh_(float x){ float e = fexp2(x*2.885390081777927f); return 1.f - 2.f*frcp(e+1.f); }
__device__ __forceinline__ float sigm_(float x){ return frcp(1.f + fexp2(-1.4426950408889634f*x)); }

// ---- coherent (sc1) accessors: cross-XCD stores + fallback reads ----
__device__ __forceinline__ u64 ald64(const void* p){
    return __hip_atomic_load((const u64*)p, __ATOMIC_RELAXED, __HIP_MEMORY_SCOPE_AGENT);
}
__device__ __forceinline__ u32 ald32(const void* p){
    return __hip_atomic_load((const u32*)p, __ATOMIC_RELAXED, __HIP_MEMORY_SCOPE_AGENT);
}
__device__ __forceinline__ void ast64(void* p, u64 v){
    __hip_atomic_store((u64*)p, v, __ATOMIC_RELAXED, __HIP_MEMORY_SCOPE_AGENT);
}
__device__ __forceinline__ void ast32(void* p, u32 v){
    __hip_atomic_store((u32*)p, v, __ATOMIC_RELAXED, __HIP_MEMORY_SCOPE_AGENT);
}

// ---- JAX partitionable Threefry-2x32, key(1)=(0,1), ctr=(0,j), fold o0^o1 ----
__device__ __forceinline__ u32 rotl32_(u32 x, int r){ return (x << r) | (x >> (32 - r)); }
__device__ bool tf_bit(u32 j){
    const u32 k0 = 0u, k1 = 1u, k2 = 0x1BD11BDAu ^ 0u ^ 1u;
    const int R0[4] = {13,15,26,6}, R1[4] = {17,29,16,24};
    u32 x0 = 0u, x1 = j;
    x0 += k0; x1 += k1;
    for(int i=0;i<4;i++){ x0 += x1; x1 = rotl32_(x1,R0[i]); x1 ^= x0; }
    x0 += k1; x1 += k2 + 1u;
    for(int i=0;i<4;i++){ x0 += x1; x1 = rotl32_(x1,R1[i]); x1 ^= x0; }
    x0 += k2; x1 += k0 + 2u;
    for(int i=0;i<4;i++){ x0 += x1; x1 = rotl32_(x1,R0[i]); x1 ^= x0; }
    x0 += k0; x1 += k1 + 3u;
    for(int i=0;i<4;i++){ x0 += x1; x1 = rotl32_(x1,R1[i]); x1 ^= x0; }
    x0 += k1; x1 += k2 + 4u;
    for(int i=0;i<4;i++){ x0 += x1; x1 = rotl32_(x1,R0[i]); x1 ^= x0; }
    x0 += k2; x1 += k0 + 5u;
    return (((x0 ^ x1) >> 31) == 0u);
}

// ---- two-level grid barrier (fallback path only) ----
__device__ __forceinline__ void gridbar(u32* sync){
    asm volatile("s_waitcnt vmcnt(0)" ::: "memory");
    __syncthreads();
    if(threadIdx.x == 0){
        u32* cnt  = sync;
        u32* gen  = sync + 32;
        u32* gcnt = sync + 64 + (blockIdx.x >> 5)*32;
        u32 g = __hip_atomic_load(gen, __ATOMIC_RELAXED, __HIP_MEMORY_SCOPE_AGENT);
        u32 a = __hip_atomic_fetch_add(gcnt, 1u, __ATOMIC_RELAXED, __HIP_MEMORY_SCOPE_AGENT);
        bool done = false;
        if(a == 31u){
            __hip_atomic_store(gcnt, 0u, __ATOMIC_RELAXED, __HIP_MEMORY_SCOPE_AGENT);
            asm volatile("s_waitcnt vmcnt(0)" ::: "memory");
            u32 b = __hip_atomic_fetch_add(cnt, 1u, __ATOMIC_RELAXED, __HIP_MEMORY_SCOPE_AGENT);
            if(b == 7u){
                __hip_atomic_store(cnt, 0u, __ATOMIC_RELAXED, __HIP_MEMORY_SCOPE_AGENT);
                asm volatile("s_waitcnt vmcnt(0)" ::: "memory");
                __hip_atomic_store(gen, g + 1u, __ATOMIC_RELAXED, __HIP_MEMORY_SCOPE_AGENT);
                done = true;
            }
        }
        if(!done)
            while(__hip_atomic_load(gen, __ATOMIC_RELAXED, __HIP_MEMORY_SCOPE_AGENT) == g)
                __builtin_amdgcn_s_sleep(1);
    }
    __syncthreads();
}

// ---- producer-counting flag sync (pipelined path) ----
__device__ __forceinline__ void flag_signal(u32* f){
    asm volatile("s_waitcnt vmcnt(0)" ::: "memory");   // drain this wave's sc1 stores
    __syncthreads();                                    // all waves drained
    if(threadIdx.x == 0)
        __hip_atomic_fetch_add(f, 1u, __ATOMIC_RELAXED, __HIP_MEMORY_SCOPE_AGENT);
}
__device__ __forceinline__ void flag_wait(u32* f, u32 target){
    if(threadIdx.x == 0){
        while(__hip_atomic_load(f, __ATOMIC_RELAXED, __HIP_MEMORY_SCOPE_AGENT) < target)
            __builtin_amdgcn_s_sleep(1);
    }
    __syncthreads();
}

// ---- f32 -> bf16 convert (grid-stride) ----
__global__ void k_cvt(const float* __restrict__ in, u16* __restrict__ out, int n){
    int i = blockIdx.x*blockDim.x + threadIdx.x;
    int st = gridDim.x*blockDim.x;
    for(; i < n; i += st) out[i] = f2b(in[i]);
}

// ---- transpose + convert: in [R][C] f32 -> out [C][R] bf16 ----
__global__ void k_cvt_t(const float* __restrict__ in, u16* __restrict__ out, int R, int C){
    __shared__ float tile[32][33];
    int bx = blockIdx.x, by = blockIdx.y;
    int tx = threadIdx.x, ty = threadIdx.y;   // 32 x 8
    for(int j = 0; j < 32; j += 8) tile[ty+j][tx] = in[(by*32+ty+j)*C + bx*32+tx];
    __syncthreads();
    for(int j = 0; j < 32; j += 8) out[(bx*32+ty+j)*R + by*32+tx] = f2b(tile[tx][ty+j]);
}

// ---- init: h0 (f32 + bf16 into hrot slot 0); outs[:,0,:] = input row 0; zero sync+flags ----
__global__ void k_init(const float* __restrict__ hidden, const float* __restrict__ input,
                       float* __restrict__ h0f, u16* __restrict__ h0b, float* __restrict__ out,
                       u32* __restrict__ sync){
    int i = blockIdx.x*blockDim.x + threadIdx.x;   // 65536
    int b = i >> 10, d = i & 1023;
    float h = hidden[d*64 + b];
    h0f[i] = h; h0b[i] = f2b(h);
    out[(long)b*kOutB + d] = input[(long)b*kOutB + d];
    if(i < 4096) sync[i] = 0u;
}

// ---- enc_proj = encb [16384,1024] @ wencT (N,K) -> epb bf16 (one-time) ----
__global__ __launch_bounds__(256) void k_gemm_ep(const u16* __restrict__ A, const u16* __restrict__ BT,
                                                 u16* __restrict__ Cb){
    int m0 = blockIdx.x*64, n0 = blockIdx.y*64;
    int w = threadIdx.x >> 6, l = threadIdx.x & 63;
    int r0 = l & 15, kh = (l >> 4) * 8;
    const u16* arow = A + (long)(m0 + w*16 + r0)*1024 + kh;
    f32x4 acc[4] = {};
    for(int k0 = 0; k0 < 1024; k0 += 32){
        short8 a = *(const short8*)(arow + k0);
        #pragma unroll
        for(int j = 0; j < 4; ++j){
            short8 b = *(const short8*)(BT + (long)(n0 + j*16 + r0)*1024 + k0 + kh);
            acc[j] = MFMA(a, b, acc[j]);
        }
    }
    int orow = m0 + w*16 + (l>>4)*4;
    int ocol = n0 + (l & 15);
    #pragma unroll
    for(int j = 0; j < 4; ++j)
        #pragma unroll
        for(int r = 0; r < 4; ++r)
            Cb[(long)(orow + r)*1024 + ocol + j*16] = f2b(acc[j][r]);
}

// ================= persistent step kernel: 255 steps, 4 phases/step =================
// 256 blocks x 256 thr. Flag-pipelined quadrants when rotation fits; global bars else.
// L2 tenant policy: GRU weights + wdecT stay cached; enc reads are NONTEMPORAL
// (evict-first) so the two big re-read streams stop thrashing each other.
__global__ __launch_bounds__(NTHR, 1) void k_steps(
        const u16* __restrict__ epb, const float* __restrict__ input, const u16* __restrict__ encb,
        const u16* __restrict__ wihb, const u16* __restrict__ whhb, const u16* __restrict__ wdecT,
        const float* __restrict__ bih, const float* __restrict__ bhh,
        const float* __restrict__ vv, const int* __restrict__ lengths,
        u16* __restrict__ hWrot, long hWstride,
        float* __restrict__ enyrot, long enystride,
        u16* __restrict__ crot, const float* __restrict__ hf0, u16* __restrict__ hrot,
        float* __restrict__ out, u32* __restrict__ sync){
    extern __shared__ char smem[];
    u16*   s_ep = (u16*)smem;                          // [64][1024] bf16 = 128 KB
    float* sB   = (float*)(smem + 131072);             // [4][256] f32 = 4 KB
    float* sA   = (float*)(smem + 135168);             // [256] f32
    float* sRed = (float*)(smem + 136192);             // [16] f32
    f32x4* sAcc = (f32x4*)(smem + 136256);             // [4][6][64] f32x4 = 24 KB

    const int bid = blockIdx.x, tid = threadIdx.x;
    const int w = tid >> 6, l = tid & 63;
    const int r0 = l & 15, kh = (l >> 4) * 8;
    const int rg = bid >> 6, cg = bid & 63;            // P1/P4 tiling
    const int p2_b = bid >> 2, p2_sq = bid & 3;        // P2/P3 tiling
    const bool useFlags = (hWstride != 0);

    // flag region (disjoint from gridbar region): one counter per 128B
    u32* fbase = sync + 1024;
    u32* f_h = fbase +        rg*32;     // P4 done (h rows rg)      : 64/step
    u32* f_w = fbase + 128  + rg*32;     // P1 done (hW rows rg)     : 64/step
    u32* f_c = fbase + 256  + rg*32;     // P3 done (ctx rows rg)    : 64/step
    u32* f_e = fbase + 512  + p2_b*32;   // P2 done (eny row b)      : 4/step

    const int p2_len = lengths[p2_b];
    float rv[16];
    #pragma unroll
    for(int j = 0; j < 16; ++j) rv[j] = vv[l*16 + j];

    // ---- preload ep slice into LDS (once) ----
    {
        const u16* src = epb + (long)(p2_b*256 + p2_sq*64)*1024;
        for(int i = tid; i < 8192; i += NTHR)
            *(short8*)(s_ep + i*8) = *(const short8*)(src + i*8);
    }
    __syncthreads();

    // ---- hoisted constants ----
    const u16* p1_brow = wdecT + (long)(cg*16 + r0)*1024 + w*256 + kh;
    const long p1_aoff = (long)(rg*16 + r0)*1024 + w*256 + kh;
    const int kxb = w*512, khb = w*256;
    const u16* b_wr = wihb + (long)(       cg*16 + r0)*2048 + kxb + kh;
    const u16* b_wz = wihb + (long)(1024 + cg*16 + r0)*2048 + kxb + kh;
    const u16* b_wn = wihb + (long)(2048 + cg*16 + r0)*2048 + kxb + kh;
    const u16* b_vr = whhb + (long)(       cg*16 + r0)*1024 + khb + kh;
    const u16* b_vz = whhb + (long)(1024 + cg*16 + r0)*1024 + khb + kh;
    const u16* b_vn = whhb + (long)(2048 + cg*16 + r0)*1024 + khb + kh;
    const long a_row_off = (long)(rg*16 + r0)*1024;     // into h/ctx slots
    const float* g_inf = input + (long)(rg*16 + r0)*kOutB;  // f32 teach rows
    const int ucol = cg*16 + (l & 15);
    const float bir = bih[ucol], biz = bih[1024+ucol], bin_ = bih[2048+ucol];
    const float bhr = bhh[ucol], bhz = bhh[1024+ucol], bhn = bhh[2048+ucol];
    const int erow = rg*16 + (l>>4)*4;                  // epilogue rows (wave 0)
    float hold[4];
    #pragma unroll
    for(int r = 0; r < 4; ++r) hold[r] = hf0[(erow + r)*1024 + ucol];

    for(int t = 1; t < 256; ++t){
        const u16* hbo = hrot + (size_t)(t-1)*65536;    // h_{t-1} bf16 (fresh slot)
        u16*       hbn = hrot + (size_t)t*65536;        // h_t bf16
        u16*       ctxt = crot + (size_t)(t-1)*65536;   // ctx slot for step t
        u16*       hWt  = hWrot  + (size_t)(t-1)*hWstride;   // bf16 [64][1024]
        float*     enyt = enyrot + (size_t)(t-1)*enystride;
        // ---- P1: hW[16rg..+16][16cg..+16] = hb @ wdecT, K-split 4 waves ----
        if(useFlags) flag_wait(f_h, 64u*(u32)(t-1));
        {
            const u16* arow = hbo + p1_aoff;
            f32x4 acc = {};
            #pragma unroll
            for(int k0 = 0; k0 < 256; k0 += 32)
                acc = MFMA(*(const short8*)(arow + k0), *(const short8*)(p1_brow + k0), acc);
            sAcc[w*64 + l] = acc;
            __syncthreads();
            if(w == 0){
                f32x4 s = sAcc[l];
                s += sAcc[64 + l]; s += sAcc[128 + l]; s += sAcc[192 + l];
                #pragma unroll
                for(int r = 0; r < 4; ++r){
                    u32 mb = (u32)f2b(s[r]);
                    u32 ob = (u32)__shfl_xor((int)mb, 1);
                    if(!(l & 1))
                        ast32((u32*)hWt + (((erow + r)*1024 + cg*16 + (l & 15)) >> 1), mb | (ob << 16));
                }
            }
        }
        if(useFlags) flag_signal(f_w); else gridbar(sync);
        // ---- P2: energy[b, s-quarter] from LDS ep + bf16 hW ----
        if(useFlags) flag_wait(f_w, 64u*(u32)t);
        {
            float rh[16];
            const u16* hp = hWt + p2_b*1024 + l*16;
            if(useFlags){
                short8 h0 = *(const short8*)(hp);
                short8 h1 = *(const short8*)(hp + 8);
                #pragma unroll
                for(int j = 0; j < 8; ++j){ rh[j] = b2f((u16)h0[j]); rh[8+j] = b2f((u16)h1[j]); }
            } else {
                #pragma unroll
                for(int j4 = 0; j4 < 4; ++j4){
                    u64 q = ald64(hp + j4*4);
                    rh[j4*4+0] = b2f((u16)(q      )); rh[j4*4+1] = b2f((u16)(q >> 16));
                    rh[j4*4+2] = b2f((u16)(q >> 32)); rh[j4*4+3] = b2f((u16)(q >> 48));
                }
            }
            const u16* lrow = s_ep + (w*16)*1024 + l*16;
            for(int si = 0; si < 16; ++si){
                int s = p2_sq*64 + w*16 + si;
                short8 q0 = *(const short8*)(lrow + si*1024);
                short8 q1 = *(const short8*)(lrow + si*1024 + 8);
                float acc = 0.f;
                #pragma unroll
                for(int j = 0; j < 8; ++j) acc += rv[j]   * tanh_(b2f((u16)q0[j]) + rh[j]);
                #pragma unroll
                for(int j = 0; j < 8; ++j) acc += rv[8+j] * tanh_(b2f((u16)q1[j]) + rh[8+j]);
                #pragma unroll
                for(int off = 32; off; off >>= 1) acc += __shfl_xor(acc, off);
                if(l == 0){
                    float val = (s < p2_len) ? acc : -1e9f;
                    ast32(enyt + p2_b*256 + s, __float_as_uint(val));
                }
            }
        }
        if(useFlags) flag_signal(f_e); else gridbar(sync);
        // ---- P3: softmax + ctx[b, d-quarter]; NONTEMPORAL enc reads (protect L2 weights) ----
        if(useFlags) flag_wait(f_e, 4u*(u32)t);
        {
            float e = useFlags ? enyt[p2_b*256 + tid]
                               : __uint_as_float(ald32(enyt + p2_b*256 + tid));
            float m = e;
            #pragma unroll
            for(int off = 32; off; off >>= 1) m = fmaxf(m, __shfl_xor(m, off));
            if(l == 0) sRed[w] = m;
            __syncthreads();
            m = fmaxf(fmaxf(sRed[0], sRed[1]), fmaxf(sRed[2], sRed[3]));
            float pp = fexp2((e - m)*1.4426950408889634f);
            sA[tid] = pp;
            float sm = pp;
            #pragma unroll
            for(int off = 32; off; off >>= 1) sm += __shfl_xor(sm, off);
            if(l == 0) sRed[4 + w] = sm;
            __syncthreads();
            float inv = 1.f / (sRed[4] + sRed[5] + sRed[6] + sRed[7]);
            const int half = l >> 5, cl = l & 31;
            const u16* ebase = encb + (long)p2_b*262144 + p2_sq*256 + cl*8;
            float acc[8] = {};
            #pragma unroll 8
            for(int i = 0; i < 32; ++i){
                int s = w*64 + i*2 + half;
                float ps = sA[s];
                short8 q = __builtin_nontemporal_load((const short8*)(ebase + (long)s*1024));
                #pragma unroll
                for(int j = 0; j < 8; ++j) acc[j] += ps*b2f((u16)q[j]);
            }
            #pragma unroll
            for(int j = 0; j < 8; ++j) acc[j] += __shfl_xor(acc[j], 32);
            if(half == 0){
                #pragma unroll
                for(int j = 0; j < 8; ++j) sB[w*256 + cl*8 + j] = acc[j];
            }
            __syncthreads();
            float c = (sB[tid] + sB[256+tid] + sB[512+tid] + sB[768+tid]) * inv;
            u32 cb = (u32)f2b(c);
            u32 ob = (u32)__shfl_xor((int)cb, 1);
            if(!(tid & 1))
                ast32((u32*)ctxt + ((p2_b*1024 + p2_sq*256 + tid) >> 1), cb | (ob << 16));
        }
        if(useFlags) flag_signal(f_c); else gridbar(sync);
        // ---- P4: GRU tile (rg,cg): 16 b-rows x (16 u-cols x 3 gates), K-split 4 waves ----
        if(useFlags) flag_wait(f_c, 64u*(u32)t);
        {
            const bool useTeach = (t == 1) || tf_bit((u32)(t - 1));
            f32x4 a_r = {}, a_z = {}, a_n = {};
            if(w < 2){
                if(useTeach){
                    const float* sf = g_inf + (long)(t - 1)*1024 + kxb + kh;
                    for(int k0 = 0; k0 < 512; k0 += 32){
                        f32x4 u0q = *(const f32x4*)(sf + k0);
                        f32x4 u1q = *(const f32x4*)(sf + k0 + 4);
                        short8 a;
                        a[0]=(short)f2b(u0q.x); a[1]=(short)f2b(u0q.y);
                        a[2]=(short)f2b(u0q.z); a[3]=(short)f2b(u0q.w);
                        a[4]=(short)f2b(u1q.x); a[5]=(short)f2b(u1q.y);
                        a[6]=(short)f2b(u1q.z); a[7]=(short)f2b(u1q.w);
                        a_r = MFMA(a, *(const short8*)(b_wr + k0), a_r);
                        a_z = MFMA(a, *(const short8*)(b_wz + k0), a_z);
                        a_n = MFMA(a, *(const short8*)(b_wn + k0), a_n);
                    }
                } else {
                    const u16* ar = hbo + a_row_off + kxb + kh;
                    for(int k0 = 0; k0 < 512; k0 += 32){
                        short8 a = *(const short8*)(ar + k0);
                        a_r = MFMA(a, *(const short8*)(b_wr + k0), a_r);
                        a_z = MFMA(a, *(const short8*)(b_wz + k0), a_z);
                        a_n = MFMA(a, *(const short8*)(b_wn + k0), a_n);
                    }
                }
            } else {
                const u16* ar = ctxt + a_row_off + (kxb - 1024) + kh;
                for(int k0 = 0; k0 < 512; k0 += 32){
                    short8 a = *(const short8*)(ar + k0);
                    a_r = MFMA(a, *(const short8*)(b_wr + k0), a_r);
                    a_z = MFMA(a, *(const short8*)(b_wz + k0), a_z);
                    a_n = MFMA(a, *(const short8*)(b_wn + k0), a_n);
                }
            }
            f32x4 h_r = {}, h_z = {}, h_n = {};
            {
                const u16* ah = hbo + a_row_off + khb + kh;
                #pragma unroll
                for(int k0 = 0; k0 < 256; k0 += 32){
                    short8 h = *(const short8*)(ah + k0);
                    h_r = MFMA(h, *(const short8*)(b_vr + k0), h_r);
                    h_z = MFMA(h, *(const short8*)(b_vz + k0), h_z);
                    h_n = MFMA(h, *(const short8*)(b_vn + k0), h_n);
                }
            }
            sAcc[(w*6+0)*64 + l] = a_r;
            sAcc[(w*6+1)*64 + l] = a_z;
            sAcc[(w*6+2)*64 + l] = a_n;
            sAcc[(w*6+3)*64 + l] = h_r;
            sAcc[(w*6+4)*64 + l] = h_z;
            sAcc[(w*6+5)*64 + l] = h_n;
            __syncthreads();
            if(w == 0){
                f32x4 air = sAcc[0*64+l] + sAcc[6*64+l] + sAcc[12*64+l] + sAcc[18*64+l];
                f32x4 aiz = sAcc[1*64+l] + sAcc[7*64+l] + sAcc[13*64+l] + sAcc[19*64+l];
                f32x4 ain = sAcc[2*64+l] + sAcc[8*64+l] + sAcc[14*64+l] + sAcc[20*64+l];
                f32x4 ahr = sAcc[3*64+l] + sAcc[9*64+l] + sAcc[15*64+l] + sAcc[21*64+l];
                f32x4 ahz = sAcc[4*64+l] + sAcc[10*64+l] + sAcc[16*64+l] + sAcc[22*64+l];
                f32x4 ahn = sAcc[5*64+l] + sAcc[11*64+l] + sAcc[17*64+l] + sAcc[23*64+l];
                #pragma unroll
                for(int r = 0; r < 4; ++r){
                    int b = erow + r;
                    float rgt = sigm_(air[r] + bir + ahr[r] + bhr);
                    float z   = sigm_(aiz[r] + biz + ahz[r] + bhz);
                    float n   = tanh_(ain[r] + bin_ + rgt*(ahn[r] + bhn));
                    float hn = (1.f - z)*n + z*hold[r];
                    hold[r] = hn;
                    __builtin_nontemporal_store(hn, &out[(long)b*kOutB + (long)t*1024 + ucol]);
                    u32 mb = (u32)f2b(hn);
                    u32 ob = (u32)__shfl_xor((int)mb, 1);
                    if(!(l & 1))
                        ast32((u32*)hbn + ((b*1024 + ucol) >> 1), mb | (ob << 16));
                }
            }
        }
        if(useFlags) flag_signal(f_h); else gridbar(sync);
    }
}

extern "C" void kernel_launch(void* const* d_in, const int* in_sizes, int n_in,
                              void* d_out, int out_size, void* d_ws, size_t ws_size,
                              hipStream_t stream){
    (void)in_sizes; (void)n_in; (void)out_size;
    const float* input    = (const float*)d_in[0];   // [64,256,1024]
    const float* hidden   = (const float*)d_in[1];   // [1024,64]
    const float* enc_outs = (const float*)d_in[2];   // [64,256,1024]
    const int*   lengths  = (const int*)  d_in[3];   // [64]
    const float* W_enc    = (const float*)d_in[4];   // [1024,1024] (K,N)
    const float* W_dec    = (const float*)d_in[5];   // [1024,1024] (K,N)
    const float* v        = (const float*)d_in[6];   // [1024]
    const float* W_ih     = (const float*)d_in[7];   // [3072,2048] (N,K)
    const float* W_hh     = (const float*)d_in[8];   // [3072,1024] (N,K)
    const float* b_ih     = (const float*)d_in[9];
    const float* b_hh     = (const float*)d_in[10];
    float* out = (float*)d_out;                      // [64,256,1024]

    // ---- workspace carve ----
    char* p = (char*)d_ws;
    auto alloc = [&](size_t bytes){ void* r = (void*)p; p += (bytes + 255) & ~(size_t)255; return r; };
    u16* epb   = (u16*)alloc((size_t)16384*1024*2);   // enc_proj bf16
    u16* encb  = (u16*)alloc((size_t)16384*1024*2);   // encoder_outs bf16
    u16* wihb  = (u16*)alloc((size_t)3072*2048*2);
    u16* whhb  = (u16*)alloc((size_t)3072*1024*2);
    u16* wencT = (u16*)alloc((size_t)1024*1024*2);
    u16* wdecT = (u16*)alloc((size_t)1024*1024*2);
    float* hf0 = (float*)alloc((size_t)64*1024*4);
    u16* hrot  = (u16*)alloc((size_t)256*65536*2);    // h bf16, fresh slot per step
    u16* crot  = (u16*)alloc((size_t)255*65536*2);    // ctx bf16, fresh slot per step
    u32* sync  = (u32*)alloc(16384);
    // rotating hW(bf16)/eny(f32) if workspace allows -> flag-pipelined mode
    size_t used = (size_t)(p - (char*)d_ws);
    size_t rotBytes = ((size_t)255*65536*2 + 256) + ((size_t)255*16384*4 + 256);
    long hWstride, enystride;
    u16 *hWrot; float *enyrot;
    if(used + rotBytes <= ws_size){
        hWrot  = (u16*)  alloc((size_t)255*65536*2);
        enyrot = (float*)alloc((size_t)255*16384*4);
        hWstride = 65536; enystride = 16384;
    } else {
        hWrot  = (u16*)  alloc((size_t)65536*2);
        enyrot = (float*)alloc((size_t)16384*4);
        hWstride = 0; enystride = 0;
    }
    if((size_t)(p - (char*)d_ws) > ws_size) return;

    // ---- one-time prep ----
    k_cvt<<<2048, 256, 0, stream>>>(enc_outs, encb, 16384*1024);
    k_cvt<<<1024, 256, 0, stream>>>(W_ih,     wihb, 3072*2048);
    k_cvt<<<512,  256, 0, stream>>>(W_hh,     whhb, 3072*1024);
    k_cvt_t<<<dim3(32,32), dim3(32,8), 0, stream>>>(W_enc, wencT, 1024, 1024);
    k_cvt_t<<<dim3(32,32), dim3(32,8), 0, stream>>>(W_dec, wdecT, 1024, 1024);
    k_init<<<256, 256, 0, stream>>>(hidden, input, hf0, hrot, out, sync);
    k_gemm_ep<<<dim3(256,16), 256, 0, stream>>>(encb, wencT, epb);

    // ---- all 255 steps in one persistent kernel ----
    hipFuncSetAttribute((const void*)k_steps, hipFuncAttributeMaxDynamicSharedMemorySize, SMEM_BYTES);
    k_steps<<<NBLK, NTHR, SMEM_BYTES, stream>>>(epb, input, encb, wihb, whhb, wdecT,
                                                b_ih, b_hh, v, lengths,
                                                hWrot, hWstride, enyrot, enystride,
                                                crot, hf0, hrot,
                                                out, sync);
}

// Round 18
// 9658.091 us; speedup vs baseline: 1.0810x; 1.0810x over previous
//
#include <hip/hip_runtime.h>
#include <stdint.h>

typedef unsigned short u16;
typedef unsigned int   u32;
typedef unsigned long long u64;
typedef __attribute__((ext_vector_type(8))) short short8;
typedef __attribute__((ext_vector_type(4))) float f32x4;

#define MFMA(a,b,c) __builtin_amdgcn_mfma_f32_16x16x32_bf16((a),(b),(c),0,0,0)
#define NBLK 256
#define NTHR 512
// LDS: ep 128K | union(sAcc 24K, sB 8K) | sA 1K | sRed 64B  = 156736 <= 163840
#define SMEM_BYTES 156736

static const long kOutB = 256*1024;   // per-batch stride in out/input [64,256,1024]

__device__ __forceinline__ float b2f(u16 v){ union{u32 u; float f;} c; c.u = ((u32)v)<<16; return c.f; }
__device__ __forceinline__ u16 f2b(float f){ union{float f; u32 u;} c; c.f = f; u32 r = c.u + 0x7FFFu + ((c.u>>16)&1u); return (u16)(r>>16); }
__device__ __forceinline__ float fexp2(float x){ return __builtin_amdgcn_exp2f(x); }
__device__ __forceinline__ float frcp(float x){ return __builtin_amdgcn_rcpf(x); }
__device__ __forceinline__ float tanh_(float x){ float e = fexp2(x*2.885390081777927f); return 1.f - 2.f*frcp(e+1.f); }
__device__ __forceinline__ float sigm_(float x){ return frcp(1.f + fexp2(-1.4426950408889634f*x)); }

// ---- coherent (sc1) accessors: cross-XCD stores + fallback reads ----
__device__ __forceinline__ u64 ald64(const void* p){
    return __hip_atomic_load((const u64*)p, __ATOMIC_RELAXED, __HIP_MEMORY_SCOPE_AGENT);
}
__device__ __forceinline__ u32 ald32(const void* p){
    return __hip_atomic_load((const u32*)p, __ATOMIC_RELAXED, __HIP_MEMORY_SCOPE_AGENT);
}
__device__ __forceinline__ void ast32(void* p, u32 v){
    __hip_atomic_store((u32*)p, v, __ATOMIC_RELAXED, __HIP_MEMORY_SCOPE_AGENT);
}

// ---- JAX partitionable Threefry-2x32, key(1)=(0,1), ctr=(0,j), fold o0^o1 ----
__device__ __forceinline__ u32 rotl32_(u32 x, int r){ return (x << r) | (x >> (32 - r)); }
__device__ bool tf_bit(u32 j){
    const u32 k0 = 0u, k1 = 1u, k2 = 0x1BD11BDAu ^ 0u ^ 1u;
    const int R0[4] = {13,15,26,6}, R1[4] = {17,29,16,24};
    u32 x0 = 0u, x1 = j;
    x0 += k0; x1 += k1;
    for(int i=0;i<4;i++){ x0 += x1; x1 = rotl32_(x1,R0[i]); x1 ^= x0; }
    x0 += k1; x1 += k2 + 1u;
    for(int i=0;i<4;i++){ x0 += x1; x1 = rotl32_(x1,R1[i]); x1 ^= x0; }
    x0 += k2; x1 += k0 + 2u;
    for(int i=0;i<4;i++){ x0 += x1; x1 = rotl32_(x1,R0[i]); x1 ^= x0; }
    x0 += k0; x1 += k1 + 3u;
    for(int i=0;i<4;i++){ x0 += x1; x1 = rotl32_(x1,R1[i]); x1 ^= x0; }
    x0 += k1; x1 += k2 + 4u;
    for(int i=0;i<4;i++){ x0 += x1; x1 = rotl32_(x1,R0[i]); x1 ^= x0; }
    x0 += k2; x1 += k0 + 5u;
    return (((x0 ^ x1) >> 31) == 0u);
}

// ---- two-level grid barrier (fallback path only) ----
__device__ __forceinline__ void gridbar(u32* sync){
    asm volatile("s_waitcnt vmcnt(0)" ::: "memory");
    __syncthreads();
    if(threadIdx.x == 0){
        u32* cnt  = sync;
        u32* gen  = sync + 32;
        u32* gcnt = sync + 64 + (blockIdx.x >> 5)*32;
        u32 g = __hip_atomic_load(gen, __ATOMIC_RELAXED, __HIP_MEMORY_SCOPE_AGENT);
        u32 a = __hip_atomic_fetch_add(gcnt, 1u, __ATOMIC_RELAXED, __HIP_MEMORY_SCOPE_AGENT);
        bool done = false;
        if(a == 31u){
            __hip_atomic_store(gcnt, 0u, __ATOMIC_RELAXED, __HIP_MEMORY_SCOPE_AGENT);
            asm volatile("s_waitcnt vmcnt(0)" ::: "memory");
            u32 b = __hip_atomic_fetch_add(cnt, 1u, __ATOMIC_RELAXED, __HIP_MEMORY_SCOPE_AGENT);
            if(b == 7u){
                __hip_atomic_store(cnt, 0u, __ATOMIC_RELAXED, __HIP_MEMORY_SCOPE_AGENT);
                asm volatile("s_waitcnt vmcnt(0)" ::: "memory");
                __hip_atomic_store(gen, g + 1u, __ATOMIC_RELAXED, __HIP_MEMORY_SCOPE_AGENT);
                done = true;
            }
        }
        if(!done)
            while(__hip_atomic_load(gen, __ATOMIC_RELAXED, __HIP_MEMORY_SCOPE_AGENT) == g)
                __builtin_amdgcn_s_sleep(1);
    }
    __syncthreads();
}

// ---- producer-counting flag sync (pipelined path) ----
__device__ __forceinline__ void flag_signal(u32* f){
    asm volatile("s_waitcnt vmcnt(0)" ::: "memory");   // drain this wave's sc1 stores
    __syncthreads();                                    // all waves drained
    if(threadIdx.x == 0)
        __hip_atomic_fetch_add(f, 1u, __ATOMIC_RELAXED, __HIP_MEMORY_SCOPE_AGENT);
}
__device__ __forceinline__ void flag_wait(u32* f, u32 target){
    if(threadIdx.x == 0){
        while(__hip_atomic_load(f, __ATOMIC_RELAXED, __HIP_MEMORY_SCOPE_AGENT) < target)
            __builtin_amdgcn_s_sleep(1);
    }
    __syncthreads();
}

// ---- f32 -> bf16 convert (grid-stride) ----
__global__ void k_cvt(const float* __restrict__ in, u16* __restrict__ out, int n){
    int i = blockIdx.x*blockDim.x + threadIdx.x;
    int st = gridDim.x*blockDim.x;
    for(; i < n; i += st) out[i] = f2b(in[i]);
}

// ---- transpose + convert: in [R][C] f32 -> out [C][R] bf16 ----
__global__ void k_cvt_t(const float* __restrict__ in, u16* __restrict__ out, int R, int C){
    __shared__ float tile[32][33];
    int bx = blockIdx.x, by = blockIdx.y;
    int tx = threadIdx.x, ty = threadIdx.y;   // 32 x 8
    for(int j = 0; j < 32; j += 8) tile[ty+j][tx] = in[(by*32+ty+j)*C + bx*32+tx];
    __syncthreads();
    for(int j = 0; j < 32; j += 8) out[(bx*32+ty+j)*R + by*32+tx] = f2b(tile[tx][ty+j]);
}

// ---- init: h0 (f32 + bf16 into hrot slot 0); outs[:,0,:] = input row 0; zero sync+flags ----
__global__ void k_init(const float* __restrict__ hidden, const float* __restrict__ input,
                       float* __restrict__ h0f, u16* __restrict__ h0b, float* __restrict__ out,
                       u32* __restrict__ sync){
    int i = blockIdx.x*blockDim.x + threadIdx.x;   // 65536
    int b = i >> 10, d = i & 1023;
    float h = hidden[d*64 + b];
    h0f[i] = h; h0b[i] = f2b(h);
    out[(long)b*kOutB + d] = input[(long)b*kOutB + d];
    if(i < 4096) sync[i] = 0u;
}

// ---- enc_proj = encb [16384,1024] @ wencT (N,K) -> epb bf16 (one-time) ----
__global__ __launch_bounds__(256) void k_gemm_ep(const u16* __restrict__ A, const u16* __restrict__ BT,
                                                 u16* __restrict__ Cb){
    int m0 = blockIdx.x*64, n0 = blockIdx.y*64;
    int w = threadIdx.x >> 6, l = threadIdx.x & 63;
    int r0 = l & 15, kh = (l >> 4) * 8;
    const u16* arow = A + (long)(m0 + w*16 + r0)*1024 + kh;
    f32x4 acc[4] = {};
    for(int k0 = 0; k0 < 1024; k0 += 32){
        short8 a = *(const short8*)(arow + k0);
        #pragma unroll
        for(int j = 0; j < 4; ++j){
            short8 b = *(const short8*)(BT + (long)(n0 + j*16 + r0)*1024 + k0 + kh);
            acc[j] = MFMA(a, b, acc[j]);
        }
    }
    int orow = m0 + w*16 + (l>>4)*4;
    int ocol = n0 + (l & 15);
    #pragma unroll
    for(int j = 0; j < 4; ++j)
        #pragma unroll
        for(int r = 0; r < 4; ++r)
            Cb[(long)(orow + r)*1024 + ocol + j*16] = f2b(acc[j][r]);
}

// ================= persistent step kernel: 255 steps, 4 phases/step =================
// 256 blocks x 512 thr (8 waves/CU). Streaming phases P2/P3 use all 8 waves (2x TLP +
// 16-deep unroll on the dominant enc stream); P1/P4 keep the proven 4-wave form.
// Flag-pipelined quadrants when rotation fits; global bars else.
__global__ __launch_bounds__(NTHR, 1) void k_steps(
        const u16* __restrict__ epb, const float* __restrict__ input, const u16* __restrict__ encb,
        const u16* __restrict__ wihb, const u16* __restrict__ whhb, const u16* __restrict__ wdecT,
        const float* __restrict__ bih, const float* __restrict__ bhh,
        const float* __restrict__ vv, const int* __restrict__ lengths,
        u16* __restrict__ hWrot, long hWstride,
        float* __restrict__ enyrot, long enystride,
        u16* __restrict__ crot, const float* __restrict__ hf0, u16* __restrict__ hrot,
        float* __restrict__ out, u32* __restrict__ sync){
    extern __shared__ char smem[];
    u16*   s_ep = (u16*)smem;                          // [64][1024] bf16 = 128 KB
    f32x4* sAcc = (f32x4*)(smem + 131072);             // [4][6][64] f32x4 = 24 KB (P1/P4)
    float* sB   = (float*)(smem + 131072);             // [8][256] f32 = 8 KB (P3, unioned)
    float* sA   = (float*)(smem + 131072 + 24576);     // [256] f32
    float* sRed = (float*)(smem + 131072 + 25600);     // [16] f32

    const int bid = blockIdx.x, tid = threadIdx.x;
    const int w = tid >> 6, l = tid & 63;
    const int r0 = l & 15, kh = (l >> 4) * 8;
    const int rg = bid >> 6, cg = bid & 63;            // P1/P4 tiling
    const int p2_b = bid >> 2, p2_sq = bid & 3;        // P2/P3 tiling
    const bool useFlags = (hWstride != 0);

    // flag region (disjoint from gridbar region): one counter per 128B
    u32* fbase = sync + 1024;
    u32* f_h = fbase +        rg*32;     // P4 done (h rows rg)      : 64/step
    u32* f_w = fbase + 128  + rg*32;     // P1 done (hW rows rg)     : 64/step
    u32* f_c = fbase + 256  + rg*32;     // P3 done (ctx rows rg)    : 64/step
    u32* f_e = fbase + 512  + p2_b*32;   // P2 done (eny row b)      : 4/step

    const int p2_len = lengths[p2_b];
    float rv[16];
    #pragma unroll
    for(int j = 0; j < 16; ++j) rv[j] = vv[l*16 + j];

    // ---- preload ep slice into LDS (once) ----
    {
        const u16* src = epb + (long)(p2_b*256 + p2_sq*64)*1024;
        for(int i = tid; i < 8192; i += NTHR)
            *(short8*)(s_ep + i*8) = *(const short8*)(src + i*8);
    }
    __syncthreads();

    // ---- hoisted constants (P1/P4 valid for w<4 only) ----
    const u16* p1_brow = wdecT + (long)(cg*16 + r0)*1024 + (w&3)*256 + kh;
    const long p1_aoff = (long)(rg*16 + r0)*1024 + (w&3)*256 + kh;
    const int kxb = (w&3)*512, khb = (w&3)*256;
    const u16* b_wr = wihb + (long)(       cg*16 + r0)*2048 + kxb + kh;
    const u16* b_wz = wihb + (long)(1024 + cg*16 + r0)*2048 + kxb + kh;
    const u16* b_wn = wihb + (long)(2048 + cg*16 + r0)*2048 + kxb + kh;
    const u16* b_vr = whhb + (long)(       cg*16 + r0)*1024 + khb + kh;
    const u16* b_vz = whhb + (long)(1024 + cg*16 + r0)*1024 + khb + kh;
    const u16* b_vn = whhb + (long)(2048 + cg*16 + r0)*1024 + khb + kh;
    const long a_row_off = (long)(rg*16 + r0)*1024;     // into h/ctx slots
    const float* g_inf = input + (long)(rg*16 + r0)*kOutB;  // f32 teach rows
    const int ucol = cg*16 + (l & 15);
    const float bir = bih[ucol], biz = bih[1024+ucol], bin_ = bih[2048+ucol];
    const float bhr = bhh[ucol], bhz = bhh[1024+ucol], bhn = bhh[2048+ucol];
    const int erow = rg*16 + (l>>4)*4;                  // epilogue rows (wave 0)
    float hold[4];
    #pragma unroll
    for(int r = 0; r < 4; ++r) hold[r] = hf0[(erow + r)*1024 + ucol];

    for(int t = 1; t < 256; ++t){
        const u16* hbo = hrot + (size_t)(t-1)*65536;    // h_{t-1} bf16 (fresh slot)
        u16*       hbn = hrot + (size_t)t*65536;        // h_t bf16
        u16*       ctxt = crot + (size_t)(t-1)*65536;   // ctx slot for step t
        u16*       hWt  = hWrot  + (size_t)(t-1)*hWstride;   // bf16 [64][1024]
        float*     enyt = enyrot + (size_t)(t-1)*enystride;
        // ---- P1 (waves 0-3): hW tile = hb @ wdecT, K-split + LDS reduce ----
        if(useFlags) flag_wait(f_h, 64u*(u32)(t-1));
        {
            if(w < 4){
                const u16* arow = hbo + p1_aoff;
                f32x4 acc = {};
                #pragma unroll
                for(int k0 = 0; k0 < 256; k0 += 32)
                    acc = MFMA(*(const short8*)(arow + k0), *(const short8*)(p1_brow + k0), acc);
                sAcc[w*64 + l] = acc;
            }
            __syncthreads();
            if(w == 0){
                f32x4 s = sAcc[l];
                s += sAcc[64 + l]; s += sAcc[128 + l]; s += sAcc[192 + l];
                #pragma unroll
                for(int r = 0; r < 4; ++r){
                    u32 mb = (u32)f2b(s[r]);
                    u32 ob = (u32)__shfl_xor((int)mb, 1);
                    if(!(l & 1))
                        ast32((u32*)hWt + (((erow + r)*1024 + cg*16 + (l & 15)) >> 1), mb | (ob << 16));
                }
            }
        }
        if(useFlags) flag_signal(f_w); else gridbar(sync);
        // ---- P2 (8 waves x 8 s-rows): energy from LDS ep + bf16 hW ----
        if(useFlags) flag_wait(f_w, 64u*(u32)t);
        {
            float rh[16];
            const u16* hp = hWt + p2_b*1024 + l*16;
            if(useFlags){
                short8 h0 = *(const short8*)(hp);
                short8 h1 = *(const short8*)(hp + 8);
                #pragma unroll
                for(int j = 0; j < 8; ++j){ rh[j] = b2f((u16)h0[j]); rh[8+j] = b2f((u16)h1[j]); }
            } else {
                #pragma unroll
                for(int j4 = 0; j4 < 4; ++j4){
                    u64 q = ald64(hp + j4*4);
                    rh[j4*4+0] = b2f((u16)(q      )); rh[j4*4+1] = b2f((u16)(q >> 16));
                    rh[j4*4+2] = b2f((u16)(q >> 32)); rh[j4*4+3] = b2f((u16)(q >> 48));
                }
            }
            const u16* lrow = s_ep + (w*8)*1024 + l*16;
            #pragma unroll
            for(int si = 0; si < 8; ++si){
                int s = p2_sq*64 + w*8 + si;
                short8 q0 = *(const short8*)(lrow + si*1024);
                short8 q1 = *(const short8*)(lrow + si*1024 + 8);
                float acc = 0.f;
                #pragma unroll
                for(int j = 0; j < 8; ++j) acc += rv[j]   * tanh_(b2f((u16)q0[j]) + rh[j]);
                #pragma unroll
                for(int j = 0; j < 8; ++j) acc += rv[8+j] * tanh_(b2f((u16)q1[j]) + rh[8+j]);
                #pragma unroll
                for(int off = 32; off; off >>= 1) acc += __shfl_xor(acc, off);
                if(l == 0){
                    float val = (s < p2_len) ? acc : -1e9f;
                    ast32(enyt + p2_b*256 + s, __float_as_uint(val));
                }
            }
        }
        if(useFlags) flag_signal(f_e); else gridbar(sync);
        // ---- P3: softmax (waves 0-3) + ctx (8 waves x 32 s, 16-deep cached enc reads) ----
        if(useFlags) flag_wait(f_e, 4u*(u32)t);
        {
            if(tid < 256){
                float e = useFlags ? enyt[p2_b*256 + tid]
                                   : __uint_as_float(ald32(enyt + p2_b*256 + tid));
                sA[tid] = e;                      // stash raw energy
                float m = e;
                #pragma unroll
                for(int off = 32; off; off >>= 1) m = fmaxf(m, __shfl_xor(m, off));
                if(l == 0) sRed[w] = m;
            }
            __syncthreads();
            float m = fmaxf(fmaxf(sRed[0], sRed[1]), fmaxf(sRed[2], sRed[3]));
            if(tid < 256){
                float pp = fexp2((sA[tid] - m)*1.4426950408889634f);
                sA[tid] = pp;
                float sm = pp;
                #pragma unroll
                for(int off = 32; off; off >>= 1) sm += __shfl_xor(sm, off);
                if(l == 0) sRed[8 + w] = sm;
            }
            __syncthreads();
            float inv = 1.f / (sRed[8] + sRed[9] + sRed[10] + sRed[11]);
            const int half = l >> 5, cl = l & 31;
            const u16* ebase = encb + (long)p2_b*262144 + p2_sq*256 + cl*8;
            float acc[8] = {};
            #pragma unroll
            for(int i = 0; i < 16; ++i){
                int s = w*32 + i*2 + half;
                float ps = sA[s];
                short8 q = *(const short8*)(ebase + (long)s*1024);
                #pragma unroll
                for(int j = 0; j < 8; ++j) acc[j] += ps*b2f((u16)q[j]);
            }
            #pragma unroll
            for(int j = 0; j < 8; ++j) acc[j] += __shfl_xor(acc[j], 32);
            __syncthreads();     // sB region free (sAcc phase over)
            if(half == 0){
                #pragma unroll
                for(int j = 0; j < 8; ++j) sB[w*256 + cl*8 + j] = acc[j];
            }
            __syncthreads();
            if(tid < 256){
                float c = 0.f;
                #pragma unroll
                for(int k = 0; k < 8; ++k) c += sB[k*256 + tid];
                c *= inv;
                u32 cb = (u32)f2b(c);
                u32 ob = (u32)__shfl_xor((int)cb, 1);
                if(!(tid & 1))
                    ast32((u32*)ctxt + ((p2_b*1024 + p2_sq*256 + tid) >> 1), cb | (ob << 16));
            }
        }
        if(useFlags) flag_signal(f_c); else gridbar(sync);
        // ---- P4 (waves 0-3): GRU tile (rg,cg), K-split + LDS reduce ----
        if(useFlags) flag_wait(f_c, 64u*(u32)t);
        {
            const bool useTeach = (t == 1) || tf_bit((u32)(t - 1));
            if(w < 4){
                f32x4 a_r = {}, a_z = {}, a_n = {};
                if(w < 2){
                    if(useTeach){
                        const float* sf = g_inf + (long)(t - 1)*1024 + kxb + kh;
                        for(int k0 = 0; k0 < 512; k0 += 32){
                            f32x4 u0q = *(const f32x4*)(sf + k0);
                            f32x4 u1q = *(const f32x4*)(sf + k0 + 4);
                            short8 a;
                            a[0]=(short)f2b(u0q.x); a[1]=(short)f2b(u0q.y);
                            a[2]=(short)f2b(u0q.z); a[3]=(short)f2b(u0q.w);
                            a[4]=(short)f2b(u1q.x); a[5]=(short)f2b(u1q.y);
                            a[6]=(short)f2b(u1q.z); a[7]=(short)f2b(u1q.w);
                            a_r = MFMA(a, *(const short8*)(b_wr + k0), a_r);
                            a_z = MFMA(a, *(const short8*)(b_wz + k0), a_z);
                            a_n = MFMA(a, *(const short8*)(b_wn + k0), a_n);
                        }
                    } else {
                        const u16* ar = hbo + a_row_off + kxb + kh;
                        for(int k0 = 0; k0 < 512; k0 += 32){
                            short8 a = *(const short8*)(ar + k0);
                            a_r = MFMA(a, *(const short8*)(b_wr + k0), a_r);
                            a_z = MFMA(a, *(const short8*)(b_wz + k0), a_z);
                            a_n = MFMA(a, *(const short8*)(b_wn + k0), a_n);
                        }
                    }
                } else {
                    const u16* ar = ctxt + a_row_off + (kxb - 1024) + kh;
                    for(int k0 = 0; k0 < 512; k0 += 32){
                        short8 a = *(const short8*)(ar + k0);
                        a_r = MFMA(a, *(const short8*)(b_wr + k0), a_r);
                        a_z = MFMA(a, *(const short8*)(b_wz + k0), a_z);
                        a_n = MFMA(a, *(const short8*)(b_wn + k0), a_n);
                    }
                }
                f32x4 h_r = {}, h_z = {}, h_n = {};
                {
                    const u16* ah = hbo + a_row_off + khb + kh;
                    #pragma unroll
                    for(int k0 = 0; k0 < 256; k0 += 32){
                        short8 h = *(const short8*)(ah + k0);
                        h_r = MFMA(h, *(const short8*)(b_vr + k0), h_r);
                        h_z = MFMA(h, *(const short8*)(b_vz + k0), h_z);
                        h_n = MFMA(h, *(const short8*)(b_vn + k0), h_n);
                    }
                }
                sAcc[(w*6+0)*64 + l] = a_r;
                sAcc[(w*6+1)*64 + l] = a_z;
                sAcc[(w*6+2)*64 + l] = a_n;
                sAcc[(w*6+3)*64 + l] = h_r;
                sAcc[(w*6+4)*64 + l] = h_z;
                sAcc[(w*6+5)*64 + l] = h_n;
            }
            __syncthreads();
            if(w == 0){
                f32x4 air = sAcc[0*64+l] + sAcc[6*64+l] + sAcc[12*64+l] + sAcc[18*64+l];
                f32x4 aiz = sAcc[1*64+l] + sAcc[7*64+l] + sAcc[13*64+l] + sAcc[19*64+l];
                f32x4 ain = sAcc[2*64+l] + sAcc[8*64+l] + sAcc[14*64+l] + sAcc[20*64+l];
                f32x4 ahr = sAcc[3*64+l] + sAcc[9*64+l] + sAcc[15*64+l] + sAcc[21*64+l];
                f32x4 ahz = sAcc[4*64+l] + sAcc[10*64+l] + sAcc[16*64+l] + sAcc[22*64+l];
                f32x4 ahn = sAcc[5*64+l] + sAcc[11*64+l] + sAcc[17*64+l] + sAcc[23*64+l];
                #pragma unroll
                for(int r = 0; r < 4; ++r){
                    int b = erow + r;
                    float rgt = sigm_(air[r] + bir + ahr[r] + bhr);
                    float z   = sigm_(aiz[r] + biz + ahz[r] + bhz);
                    float n   = tanh_(ain[r] + bin_ + rgt*(ahn[r] + bhn));
                    float hn = (1.f - z)*n + z*hold[r];
                    hold[r] = hn;
                    out[(long)b*kOutB + (long)t*1024 + ucol] = hn;
                    u32 mb = (u32)f2b(hn);
                    u32 ob = (u32)__shfl_xor((int)mb, 1);
                    if(!(l & 1))
                        ast32((u32*)hbn + ((b*1024 + ucol) >> 1), mb | (ob << 16));
                }
            }
        }
        if(useFlags) flag_signal(f_h); else gridbar(sync);
    }
}

extern "C" void kernel_launch(void* const* d_in, const int* in_sizes, int n_in,
                              void* d_out, int out_size, void* d_ws, size_t ws_size,
                              hipStream_t stream){
    (void)in_sizes; (void)n_in; (void)out_size;
    const float* input    = (const float*)d_in[0];   // [64,256,1024]
    const float* hidden   = (const float*)d_in[1];   // [1024,64]
    const float* enc_outs = (const float*)d_in[2];   // [64,256,1024]
    const int*   lengths  = (const int*)  d_in[3];   // [64]
    const float* W_enc    = (const float*)d_in[4];   // [1024,1024] (K,N)
    const float* W_dec    = (const float*)d_in[5];   // [1024,1024] (K,N)
    const float* v        = (const float*)d_in[6];   // [1024]
    const float* W_ih     = (const float*)d_in[7];   // [3072,2048] (N,K)
    const float* W_hh     = (const float*)d_in[8];   // [3072,1024] (N,K)
    const float* b_ih     = (const float*)d_in[9];
    const float* b_hh     = (const float*)d_in[10];
    float* out = (float*)d_out;                      // [64,256,1024]

    // ---- workspace carve ----
    char* p = (char*)d_ws;
    auto alloc = [&](size_t bytes){ void* r = (void*)p; p += (bytes + 255) & ~(size_t)255; return r; };
    u16* epb   = (u16*)alloc((size_t)16384*1024*2);   // enc_proj bf16
    u16* encb  = (u16*)alloc((size_t)16384*1024*2);   // encoder_outs bf16
    u16* wihb  = (u16*)alloc((size_t)3072*2048*2);
    u16* whhb  = (u16*)alloc((size_t)3072*1024*2);
    u16* wencT = (u16*)alloc((size_t)1024*1024*2);
    u16* wdecT = (u16*)alloc((size_t)1024*1024*2);
    float* hf0 = (float*)alloc((size_t)64*1024*4);
    u16* hrot  = (u16*)alloc((size_t)256*65536*2);    // h bf16, fresh slot per step
    u16* crot  = (u16*)alloc((size_t)255*65536*2);    // ctx bf16, fresh slot per step
    u32* sync  = (u32*)alloc(16384);
    // rotating hW(bf16)/eny(f32) if workspace allows -> flag-pipelined mode
    size_t used = (size_t)(p - (char*)d_ws);
    size_t rotBytes = ((size_t)255*65536*2 + 256) + ((size_t)255*16384*4 + 256);
    long hWstride, enystride;
    u16 *hWrot; float *enyrot;
    if(used + rotBytes <= ws_size){
        hWrot  = (u16*)  alloc((size_t)255*65536*2);
        enyrot = (float*)alloc((size_t)255*16384*4);
        hWstride = 65536; enystride = 16384;
    } else {
        hWrot  = (u16*)  alloc((size_t)65536*2);
        enyrot = (float*)alloc((size_t)16384*4);
        hWstride = 0; enystride = 0;
    }
    if((size_t)(p - (char*)d_ws) > ws_size) return;

    // ---- one-time prep ----
    k_cvt<<<2048, 256, 0, stream>>>(enc_outs, encb, 16384*1024);
    k_cvt<<<1024, 256, 0, stream>>>(W_ih,     wihb, 3072*2048);
    k_cvt<<<512,  256, 0, stream>>>(W_hh,     whhb, 3072*1024);
    k_cvt_t<<<dim3(32,32), dim3(32,8), 0, stream>>>(W_enc, wencT, 1024, 1024);
    k_cvt_t<<<dim3(32,32), dim3(32,8), 0, stream>>>(W_dec, wdecT, 1024, 1024);
    k_init<<<256, 256, 0, stream>>>(hidden, input, hf0, hrot, out, sync);
    k_gemm_ep<<<dim3(256,16), 256, 0, stream>>>(encb, wencT, epb);

    // ---- all 255 steps in one persistent kernel ----
    hipFuncSetAttribute((const void*)k_steps, hipFuncAttributeMaxDynamicSharedMemorySize, SMEM_BYTES);
    k_steps<<<NBLK, NTHR, SMEM_BYTES, stream>>>(epb, input, encb, wihb, whhb, wdecT,
                                                b_ih, b_hh, v, lengths,
                                                hWrot, hWstride, enyrot, enystride,
                                                crot, hf0, hrot,
                                                out, sync);
}